// Round 1
// baseline (754.290 us; speedup 1.0000x reference)
//
#include <hip/hip_runtime.h>
#include <hip/hip_bf16.h>

// Problem constants
#define B_    4
#define CI_   64
#define CO_   128
#define NIN_  65536
#define NOUT_ 16384
#define KK_   9
#define PP_   4
#define HH_   32

// Conv-kernel tiling: 128 o  x  128 n (n = mi*4+b, 32 m per block), 256 threads, 8x8 per thread.
// LDS rows stride 76 floats (=304B, 16B-aligned for float4 reads).
#define SROW  76
#define SHST  130           // epilogue bounce stride
#define LDSZ  (2*CO_*SROW*4)  // 77824 B

__device__ __forceinline__ float bf2f(__hip_bfloat16 v) { return __bfloat162float(v); }

// ---------------- small kernels ----------------

__global__ void zero_kernel(float* p, int n) {
    int i = blockIdx.x * 256 + threadIdx.x;
    if (i < n) p[i] = 0.f;
}

// a[m,k] = weight_net(off[m,k,:2]) for both off1 and off2
__global__ void wnet_kernel(const float* __restrict__ off1, const float* __restrict__ off2,
                            const float* __restrict__ w1, const float* __restrict__ b1,
                            const float* __restrict__ w2, const float* __restrict__ b2,
                            float* __restrict__ a1, float* __restrict__ a2) {
    int idx = blockIdx.x * 256 + threadIdx.x;
    if (idx >= NOUT_ * KK_) return;
    float x0 = off1[idx*2+0], x1 = off1[idx*2+1];
    float y0 = off2[idx*2+0], y1 = off2[idx*2+1];
    float bias2 = b2[0];
    float s1 = bias2, s2 = bias2;
    #pragma unroll
    for (int h = 0; h < HH_; ++h) {
        float wh0 = w1[h], wh1 = w1[HH_+h], bh = b1[h], vh = w2[h];
        s1 += fmaxf(x0*wh0 + x1*wh1 + bh, 0.f) * vh;
        s2 += fmaxf(y0*wh0 + y1*wh1 + bh, 0.f) * vh;
    }
    a1[idx] = s1;
    a2[idx] = s2;
}

// WT[k][o][i] = W[o][i][k]
__global__ void wtrans_kernel(const float* __restrict__ W, float* __restrict__ WT, int CIN) {
    int idx = blockIdx.x * 256 + threadIdx.x;
    int total = CO_ * CIN * KK_;
    if (idx >= total) return;
    int k  = idx % KK_;
    int oi = idx / KK_;
    int i  = oi % CIN;
    int o  = oi / CIN;
    WT[((size_t)k*CO_ + o)*CIN + i] = W[idx];
}

// xT[p][b][i] (bf16) = x[b][i][p] (f32); 64x64 LDS tile transpose per (p-chunk, b)
__global__ void xtrans_kernel(const float* __restrict__ x, __hip_bfloat16* __restrict__ xT) {
    __shared__ float tile[64][65];
    int p0 = blockIdx.x * 64;
    int b  = blockIdx.y;
    int t  = threadIdx.x;
    #pragma unroll
    for (int r = 0; r < 16; ++r) {
        int f = r*256 + t;
        int i = f >> 6, pp = f & 63;
        tile[i][pp] = x[((size_t)(b*CI_ + i))*NIN_ + p0 + pp];
    }
    __syncthreads();
    #pragma unroll
    for (int r = 0; r < 16; ++r) {
        int f = r*256 + t;
        int pp = f >> 6, i = f & 63;
        xT[((size_t)(p0+pp)*B_ + b)*CI_ + i] = __float2bfloat16(tile[i][pp]);
    }
}

// per-channel BN affine params from accumulated sums
__global__ void bnparams_kernel(const float* __restrict__ gsum, const float* __restrict__ gsq,
                                const float* __restrict__ g, const float* __restrict__ bb,
                                float* __restrict__ scale, float* __restrict__ bias) {
    int o = threadIdx.x;  // 128 threads
    const float inv_n = 1.f / (B_ * NOUT_);
    float mean = gsum[o] * inv_n;
    float var  = gsq[o] * inv_n - mean*mean;
    float sc   = g[o] * rsqrtf(var + 1e-5f);
    scale[o] = sc;
    bias[o]  = bb[o] - mean*sc;
}

// ---------------- conv (implicit GEMM, gather-staged) ----------------
// out[o][n] = sum_{k, i} WT[k][o][i] * ( inT[nbr[m,k]][b][i] (opt: bn+relu) * a[m,k] )
// n = mi*4 + b, block handles m0..m0+31, all o, all b.
template<int CIN, bool BN>
__global__ __launch_bounds__(256, 2) void conv_kernel(
    const __hip_bfloat16* __restrict__ inT,   // [Npts][B][CIN] bf16
    const float* __restrict__ WT,             // [K][CO][CIN] f32
    const int*   __restrict__ nbr,            // [NOUT][K]
    const float* __restrict__ amk,            // [NOUT][K]
    const float* __restrict__ bnsc, const float* __restrict__ bnbi,  // [CIN] (BN only)
    __hip_bfloat16* __restrict__ outT,        // [NOUT][B][CO] bf16 (raw, pre-BN)
    float* __restrict__ gsum, float* __restrict__ gsq) {
    extern __shared__ float lds[];
    float* Ws = lds;                 // [128 o][SROW]
    float* Gs = lds + CO_*SROW;      // [128 n][SROW]
    const int t  = threadIdx.x;
    const int m0 = blockIdx.x * 32;
    const int og = t & 15;           // o = og + 16*c
    const int ng = t >> 4;           // n = j*16 + ng

    float acc[8][8];
    #pragma unroll
    for (int c = 0; c < 8; ++c)
        #pragma unroll
        for (int j = 0; j < 8; ++j) acc[c][j] = 0.f;

    constexpr int NSLAB = (CIN/64) * KK_;
    for (int slab = 0; slab < NSLAB; ++slab) {
        const int k    = (CIN == 64) ? slab : (slab >> 1);
        const int ioff = (CIN == 64) ? 0 : ((slab & 1) << 6);
        __syncthreads();  // LDS reuse vs previous compute
        // stage Ws[o][i] = WT[k][o][ioff+i]  (coalesced reads, conflict-free writes)
        {
            const float* wsrc = WT + ((size_t)k*CO_)*CIN + ioff;
            #pragma unroll
            for (int r = 0; r < 32; ++r) {
                int f = r*256 + t;
                int o = f >> 6, i = f & 63;
                Ws[o*SROW + i] = wsrc[(size_t)o*CIN + i];
            }
        }
        // stage Gs[n][i] = bn_relu(inT[p][b][ioff+i]) * a[m,k]
        #pragma unroll 4
        for (int r = 0; r < 32; ++r) {
            int f   = r*256 + t;
            int col = f >> 6, i = f & 63;   // col = n = mi*4+b
            int mi  = col >> 2, b = col & 3;
            int m   = m0 + mi;
            int p   = nbr[m*KK_ + k];
            float av = amk[m*KK_ + k];
            float v = bf2f(inT[((size_t)p*B_ + b)*CIN + ioff + i]);
            if constexpr (BN) v = fmaxf(v*bnsc[ioff+i] + bnbi[ioff+i], 0.f);
            Gs[col*SROW + i] = v * av;
        }
        __syncthreads();
        // compute: 8x8 register tile over 64 i
        #pragma unroll 2
        for (int i4 = 0; i4 < 16; ++i4) {
            float4 wv[8], gv[8];
            #pragma unroll
            for (int c = 0; c < 8; ++c)
                wv[c] = *reinterpret_cast<const float4*>(&Ws[(og + 16*c)*SROW + i4*4]);
            #pragma unroll
            for (int j = 0; j < 8; ++j)
                gv[j] = *reinterpret_cast<const float4*>(&Gs[(j*16 + ng)*SROW + i4*4]);
            #pragma unroll
            for (int c = 0; c < 8; ++c)
                #pragma unroll
                for (int j = 0; j < 8; ++j) {
                    acc[c][j] += wv[c].x * gv[j].x;
                    acc[c][j] += wv[c].y * gv[j].y;
                    acc[c][j] += wv[c].z * gv[j].z;
                    acc[c][j] += wv[c].w * gv[j].w;
                }
        }
    }
    // epilogue: bounce to LDS for stats + coalesced transposed write
    __syncthreads();
    float* sh = lds;  // [128 n][SHST]
    #pragma unroll
    for (int c = 0; c < 8; ++c)
        #pragma unroll
        for (int j = 0; j < 8; ++j)
            sh[(j*16 + ng)*SHST + og + 16*c] = acc[c][j];
    __syncthreads();
    {   // BN statistics (f32 partials + atomics)
        int o = t & 127, h = t >> 7;
        float s = 0.f, q = 0.f;
        for (int n = h*64; n < h*64 + 64; ++n) {
            float v = sh[n*SHST + o];
            s += v; q += v*v;
        }
        atomicAdd(&gsum[o], s);
        atomicAdd(&gsq[o], q);
    }
    #pragma unroll 4
    for (int r = 0; r < 64; ++r) {
        int f = r*256 + t;               // f = n*128 + o
        int n = f >> 7, o = f & 127;
        outT[((size_t)(m0*B_) + n)*CO_ + o] = __float2bfloat16(sh[n*SHST + o]);
    }
}

// ---------------- final: identity GEMM + BN2 + add + relu ----------------
__global__ __launch_bounds__(256, 2) void final_kernel(
    const __hip_bfloat16* __restrict__ xT,     // [NIN][B][CI] bf16
    const __hip_bfloat16* __restrict__ out2T,  // [NOUT][B][CO] bf16 (raw)
    const int*   __restrict__ pool_idx,        // [NOUT][P]
    const float* __restrict__ exp_w,           // [CO][CI]
    const float* __restrict__ exp_b,           // [CO]
    const float* __restrict__ sc2, const float* __restrict__ bi2,
    float* __restrict__ out) {                 // [B][CO][NOUT]
    extern __shared__ float lds[];
    float* Es   = lds;               // [128 o][SROW] (64 i used)
    float* Pool = lds + CO_*SROW;    // [128 n][SROW]
    const int t  = threadIdx.x;
    const int m0 = blockIdx.x * 32;
    const int og = t & 15, ng = t >> 4;

    #pragma unroll
    for (int r = 0; r < 32; ++r) {   // Es[o][i] = exp_w[o][i]
        int f = r*256 + t;
        int o = f >> 6, i = f & 63;
        Es[o*SROW + i] = exp_w[f];
    }
    #pragma unroll 2
    for (int r = 0; r < 32; ++r) {   // Pool[n][i] = mean_p xT[pool_idx[m][p]][b][i]
        int f   = r*256 + t;
        int col = f >> 6, i = f & 63;
        int mi  = col >> 2, b = col & 3;
        int m   = m0 + mi;
        float s = 0.f;
        #pragma unroll
        for (int p = 0; p < PP_; ++p) {
            int pp = pool_idx[m*PP_ + p];
            s += bf2f(xT[((size_t)pp*B_ + b)*CI_ + i]);
        }
        Pool[col*SROW + i] = s * 0.25f;
    }
    __syncthreads();
    float acc[8][8];
    #pragma unroll
    for (int c = 0; c < 8; ++c)
        #pragma unroll
        for (int j = 0; j < 8; ++j) acc[c][j] = 0.f;
    #pragma unroll 2
    for (int i4 = 0; i4 < 16; ++i4) {
        float4 wv[8], gv[8];
        #pragma unroll
        for (int c = 0; c < 8; ++c)
            wv[c] = *reinterpret_cast<const float4*>(&Es[(og + 16*c)*SROW + i4*4]);
        #pragma unroll
        for (int j = 0; j < 8; ++j)
            gv[j] = *reinterpret_cast<const float4*>(&Pool[(j*16 + ng)*SROW + i4*4]);
        #pragma unroll
        for (int c = 0; c < 8; ++c)
            #pragma unroll
            for (int j = 0; j < 8; ++j) {
                acc[c][j] += wv[c].x * gv[j].x;
                acc[c][j] += wv[c].y * gv[j].y;
                acc[c][j] += wv[c].z * gv[j].z;
                acc[c][j] += wv[c].w * gv[j].w;
            }
    }
    __syncthreads();
    float* sh = lds;  // [128 n][SHST] identity (pre exp_b)
    #pragma unroll
    for (int c = 0; c < 8; ++c)
        #pragma unroll
        for (int j = 0; j < 8; ++j)
            sh[(j*16 + ng)*SHST + og + 16*c] = acc[c][j];
    __syncthreads();
    #pragma unroll 4
    for (int r = 0; r < 64; ++r) {
        int f  = r*256 + t;              // f = b*4096 + o*32 + mi  (m innermost for coalesced out)
        int b  = f >> 12;
        int o  = (f >> 5) & 127;
        int mi = f & 31;
        int n  = mi*4 + b;
        float ident = sh[n*SHST + o] + exp_b[o];
        float v2 = bf2f(out2T[((size_t)(m0+mi)*B_ + b)*CO_ + o]);
        v2 = v2 * sc2[o] + bi2[o];
        out[((size_t)(b*CO_ + o))*NOUT_ + m0 + mi] = fmaxf(v2 + ident, 0.f);
    }
}

// ---------------- launch ----------------
extern "C" void kernel_launch(void* const* d_in, const int* in_sizes, int n_in,
                              void* d_out, int out_size, void* d_ws, size_t ws_size,
                              hipStream_t stream) {
    const float* x        = (const float*)d_in[0];
    const float* off1     = (const float*)d_in[1];
    const float* off2     = (const float*)d_in[2];
    const int*   nbr1     = (const int*)  d_in[3];
    const int*   nbr2     = (const int*)  d_in[4];
    const int*   pool_idx = (const int*)  d_in[5];
    const float* wn_w1    = (const float*)d_in[6];
    const float* wn_b1    = (const float*)d_in[7];
    const float* wn_w2    = (const float*)d_in[8];
    const float* wn_b2    = (const float*)d_in[9];
    const float* W1       = (const float*)d_in[10];
    const float* W2       = (const float*)d_in[11];
    const float* bn1_g    = (const float*)d_in[12];
    const float* bn1_b    = (const float*)d_in[13];
    const float* bn2_g    = (const float*)d_in[14];
    const float* bn2_b    = (const float*)d_in[15];
    const float* exp_w    = (const float*)d_in[16];
    const float* exp_b    = (const float*)d_in[17];
    float* out = (float*)d_out;

    // workspace carve (~69.2 MB total)
    char* ws = (char*)d_ws;
    float* a1    = (float*)ws;  ws += (size_t)NOUT_*KK_*4;          // 589824
    float* a2    = (float*)ws;  ws += (size_t)NOUT_*KK_*4;
    float* W1T   = (float*)ws;  ws += (size_t)KK_*CO_*CI_*4;        // 294912
    float* W2T   = (float*)ws;  ws += (size_t)KK_*CO_*CO_*4;        // 589824
    float* stats = (float*)ws;  ws += 1024*4;                       // 4KB
    __hip_bfloat16* xT    = (__hip_bfloat16*)ws; ws += (size_t)NIN_*B_*CI_*2;   // 33.5MB
    __hip_bfloat16* out1T = (__hip_bfloat16*)ws; ws += (size_t)NOUT_*B_*CO_*2;  // 16.8MB
    __hip_bfloat16* out2T = (__hip_bfloat16*)ws; ws += (size_t)NOUT_*B_*CO_*2;  // 16.8MB

    float* sum1 = stats;       float* sq1 = stats + 128;
    float* sum2 = stats + 256; float* sq2 = stats + 384;
    float* sc1  = stats + 512; float* bi1 = stats + 640;
    float* sc2  = stats + 768; float* bi2 = stats + 896;

    hipFuncSetAttribute(reinterpret_cast<const void*>(conv_kernel<CI_, false>),
                        hipFuncAttributeMaxDynamicSharedMemorySize, LDSZ);
    hipFuncSetAttribute(reinterpret_cast<const void*>(conv_kernel<CO_, true>),
                        hipFuncAttributeMaxDynamicSharedMemorySize, LDSZ);
    hipFuncSetAttribute(reinterpret_cast<const void*>(final_kernel),
                        hipFuncAttributeMaxDynamicSharedMemorySize, LDSZ);

    zero_kernel<<<2, 256, 0, stream>>>(stats, 512);
    wnet_kernel<<<(NOUT_*KK_ + 255)/256, 256, 0, stream>>>(off1, off2, wn_w1, wn_b1, wn_w2, wn_b2, a1, a2);
    wtrans_kernel<<<(CO_*CI_*KK_ + 255)/256, 256, 0, stream>>>(W1, W1T, CI_);
    wtrans_kernel<<<(CO_*CO_*KK_ + 255)/256, 256, 0, stream>>>(W2, W2T, CO_);
    xtrans_kernel<<<dim3(NIN_/64, B_), 256, 0, stream>>>(x, xT);

    conv_kernel<CI_, false><<<NOUT_/32, 256, LDSZ, stream>>>(
        xT, W1T, nbr1, a1, nullptr, nullptr, out1T, sum1, sq1);
    bnparams_kernel<<<1, 128, 0, stream>>>(sum1, sq1, bn1_g, bn1_b, sc1, bi1);
    conv_kernel<CO_, true><<<NOUT_/32, 256, LDSZ, stream>>>(
        out1T, W2T, nbr2, a2, sc1, bi1, out2T, sum2, sq2);
    bnparams_kernel<<<1, 128, 0, stream>>>(sum2, sq2, bn2_g, bn2_b, sc2, bi2);
    final_kernel<<<NOUT_/32, 256, LDSZ, stream>>>(
        xT, out2T, pool_idx, exp_w, exp_b, sc2, bi2, out);
}

// Round 2
// 274.382 us; speedup vs baseline: 2.7491x; 2.7491x over previous
//
#include <hip/hip_runtime.h>
#include <hip/hip_bf16.h>

// Problem constants
#define B_    4
#define CI_   64
#define CO_   128
#define NIN_  65536
#define NOUT_ 16384
#define KK_   9
#define PP_   4
#define HH_   32

typedef _Float16 f16x8 __attribute__((ext_vector_type(8)));
typedef _Float16 f16x4 __attribute__((ext_vector_type(4)));
typedef float    f32x4 __attribute__((ext_vector_type(4)));

// final-kernel tiling constants (f32 vector GEMM, small)
#define SROW  76
#define SHST  130
#define LDSZ  (2*CO_*SROW*4)  // 77824 B

// ---------------- small kernels ----------------

// a[m,k] = weight_net(off[m,k,:2]) for both off1 and off2
__global__ void wnet_kernel(const float* __restrict__ off1, const float* __restrict__ off2,
                            const float* __restrict__ w1, const float* __restrict__ b1,
                            const float* __restrict__ w2, const float* __restrict__ b2,
                            float* __restrict__ a1, float* __restrict__ a2) {
    int idx = blockIdx.x * 256 + threadIdx.x;
    if (idx >= NOUT_ * KK_) return;
    float x0 = off1[idx*2+0], x1 = off1[idx*2+1];
    float y0 = off2[idx*2+0], y1 = off2[idx*2+1];
    float bias2 = b2[0];
    float s1 = bias2, s2 = bias2;
    #pragma unroll
    for (int h = 0; h < HH_; ++h) {
        float wh0 = w1[h], wh1 = w1[HH_+h], bh = b1[h], vh = w2[h];
        s1 += fmaxf(x0*wh0 + x1*wh1 + bh, 0.f) * vh;
        s2 += fmaxf(y0*wh0 + y1*wh1 + bh, 0.f) * vh;
    }
    a1[idx] = s1;
    a2[idx] = s2;
}

// Pack W into per-lane MFMA A-fragment order (fp16).
// Wf element f = (((s*2+kap)*8 + ot)*64 + l)*8 + j holds
//   A[o = ot*16 + (l&15)][kel = kap*32 + ((l>>4)&3)*8 + j] of slab s.
template<int CIN>
__global__ void wpack_kernel(const float* __restrict__ W, _Float16* __restrict__ Wf) {
    constexpr int NSLAB = (CIN/64) * KK_;
    int f = blockIdx.x * 256 + threadIdx.x;
    if (f >= NSLAB * 8192) return;
    int j   = f & 7;
    int l   = (f >> 3) & 63;
    int ot  = (f >> 9) & 7;
    int kap = (f >> 12) & 1;
    int s   = f >> 13;
    int o   = ot*16 + (l & 15);
    int kel = kap*32 + ((l >> 4) & 3)*8 + j;
    int k, i;
    if (CIN == 64) { k = s; i = kel; }
    else           { k = s >> 1; i = ((s & 1) << 6) + kel; }
    Wf[f] = (_Float16)W[((size_t)o*CIN + i)*KK_ + k];
}

// xT[p][b][i] (fp16) = x[b][i][p] (f32)
__global__ void xtrans_kernel(const float* __restrict__ x, _Float16* __restrict__ xT) {
    __shared__ float tile[64][65];
    int p0 = blockIdx.x * 64;
    int b  = blockIdx.y;
    int t  = threadIdx.x;
    #pragma unroll
    for (int r = 0; r < 16; ++r) {
        int f = r*256 + t;
        int i = f >> 6, pp = f & 63;
        tile[i][pp] = x[((size_t)(b*CI_ + i))*NIN_ + p0 + pp];
    }
    __syncthreads();
    #pragma unroll
    for (int r = 0; r < 16; ++r) {
        int f = r*256 + t;
        int pp = f >> 6, i = f & 63;
        xT[((size_t)(p0+pp)*B_ + b)*CI_ + i] = (_Float16)tile[i][pp];
    }
}

// column sums/sumsq of t[65536][128] -> pbuf[blk][256] partials (no atomics)
__global__ __launch_bounds__(256) void stats_kernel(const _Float16* __restrict__ t,
                                                    float* __restrict__ pbuf) {
    const int o = threadIdx.x & 127, rh = threadIdx.x >> 7;
    const size_t r0 = (size_t)blockIdx.x * 512;
    float s = 0.f, q = 0.f;
    for (int r = rh; r < 512; r += 2) {
        float v = (float)t[(r0 + r)*128 + o];
        s += v; q += v*v;
    }
    __shared__ float red[2][256];
    red[0][threadIdx.x] = s; red[1][threadIdx.x] = q;
    __syncthreads();
    if (rh == 0) {
        pbuf[blockIdx.x*256 + o]       = s + red[0][128 + o];
        pbuf[blockIdx.x*256 + 128 + o] = q + red[1][128 + o];
    }
}

// reduce partials -> scale/bias
__global__ void bnparams_kernel(const float* __restrict__ pbuf,
                                const float* __restrict__ g, const float* __restrict__ bb,
                                float* __restrict__ scbi) {
    int o = threadIdx.x;  // 128 threads
    float s = 0.f, q = 0.f;
    for (int blk = 0; blk < 128; ++blk) {
        s += pbuf[blk*256 + o];
        q += pbuf[blk*256 + 128 + o];
    }
    const float inv_n = 1.f / (B_ * NOUT_);
    float mean = s * inv_n;
    float var  = q * inv_n - mean*mean;
    float sc   = g[o] * rsqrtf(var + 1e-5f);
    scbi[o]       = sc;
    scbi[128 + o] = bb[o] - mean*sc;
}

// in-place BN+ReLU on t[65536][128] fp16
__global__ __launch_bounds__(256) void bnrelu_kernel(_Float16* __restrict__ t,
                                                     const float* __restrict__ scbi) {
    __shared__ float ssc[128], sbi[128];
    if (threadIdx.x < 128) {
        ssc[threadIdx.x] = scbi[threadIdx.x];
        sbi[threadIdx.x] = scbi[128 + threadIdx.x];
    }
    __syncthreads();
    size_t idx = ((size_t)blockIdx.x*256 + threadIdx.x) * 8;
    int o0 = (int)(idx & 127);
    f16x8 v = *(f16x8*)(t + idx);
    #pragma unroll
    for (int e = 0; e < 8; ++e) {
        float f = (float)v[e] * ssc[o0+e] + sbi[o0+e];
        v[e] = (_Float16)fmaxf(f, 0.f);
    }
    *(f16x8*)(t + idx) = v;
}

// ---------------- MFMA conv (implicit GEMM, gather-staged) ----------------
// out[n][o] = sum_{k,i} W[o,i,k] * a[m,k] * in[nbr[m,k]*B+b][i],  n = mi*4+b.
// Block: 128 o x 128 n, 4 waves (2x2), each wave 64x64 via 4x4 16x16x32 frags.
template<int CIN, int NSLAB>
__global__ __launch_bounds__(256, 2) void conv_mfma_kernel(
    const _Float16* __restrict__ in,    // [Npts*B][CIN]
    const _Float16* __restrict__ Wf,    // frag-packed fp16
    const int*      __restrict__ nbr,   // [NOUT][K]
    const float*    __restrict__ amk,   // [NOUT][K]
    _Float16*       __restrict__ outh)  // [NOUT*B][128] raw (pre-BN)
{
    __shared__ _Float16 Gs[128*64];     // XOR-swizzled: chunk ^= row&7
    const int t    = threadIdx.x;
    const int lane = t & 63;
    const int wid  = t >> 6;
    const int wr   = wid >> 1, wc = wid & 1;
    const int m0   = blockIdx.x * 32;
    const int l15 = lane & 15, l4 = lane >> 4, l7 = lane & 7;
    // staging assignment: thread -> (row n, half h)
    const int srow = t >> 1;
    const int sh   = t & 1;
    const int sm   = m0 + (srow >> 2);
    const int sb   = srow & 3;

    f32x4 acc[4][4];
    #pragma unroll
    for (int c = 0; c < 4; ++c)
        #pragma unroll
        for (int j = 0; j < 4; ++j)
            acc[c][j] = (f32x4){0.f, 0.f, 0.f, 0.f};

    for (int s = 0; s < NSLAB; ++s) {
        const int k    = (CIN == 64) ? s : (s >> 1);
        const int ioff = (CIN == 64) ? 0 : ((s & 1) << 6);
        // A fragments straight from global (frag-packed, coalesced, L2/L3-hot)
        f16x8 aF[2][4];
        #pragma unroll
        for (int kap = 0; kap < 2; ++kap)
            #pragma unroll
            for (int c = 0; c < 4; ++c)
                aF[kap][c] = *(const f16x8*)(Wf +
                    ((size_t)((s*2 + kap)*8 + (wr*4 + c))*64 + lane)*8);
        // gather + scale
        const int   p  = nbr[sm*KK_ + k];
        const float av = amk[sm*KK_ + k];
        const _Float16 hs = (_Float16)av;
        const _Float16* src = in + ((size_t)p*B_ + sb)*CIN + ioff + sh*32;
        f16x8 g[4];
        #pragma unroll
        for (int q = 0; q < 4; ++q) g[q] = *(const f16x8*)(src + q*8);
        __syncthreads();   // previous slab's compute done before overwrite
        #pragma unroll
        for (int q = 0; q < 4; ++q) {
            f16x8 v = g[q];
            #pragma unroll
            for (int e = 0; e < 8; ++e) v[e] = v[e] * hs;
            const int c4 = sh*4 + q;
            *(f16x8*)(Gs + srow*64 + ((c4 ^ (srow & 7)) << 3)) = v;
        }
        __syncthreads();
        // compute
        #pragma unroll
        for (int kap = 0; kap < 2; ++kap) {
            f16x8 bF[4];
            #pragma unroll
            for (int jt = 0; jt < 4; ++jt) {
                const int row = wc*64 + jt*16 + l15;
                const int ch  = (kap*4 + l4) ^ l7;   // row&7 == l7 (row base mult of 16)
                bF[jt] = *(const f16x8*)(Gs + row*64 + (ch << 3));
            }
            #pragma unroll
            for (int c = 0; c < 4; ++c)
                #pragma unroll
                for (int jt = 0; jt < 4; ++jt)
                    acc[c][jt] = __builtin_amdgcn_mfma_f32_16x16x32_f16(
                        aF[kap][c], bF[jt], acc[c][jt], 0, 0, 0);
        }
    }
    // epilogue: direct fp16 store (D: col=lane&15, row=(lane>>4)*4+reg)
    #pragma unroll
    for (int c = 0; c < 4; ++c) {
        const int o = wr*64 + c*16 + l4*4;
        #pragma unroll
        for (int jt = 0; jt < 4; ++jt) {
            const int n = wc*64 + jt*16 + l15;
            f16x4 h;
            #pragma unroll
            for (int r = 0; r < 4; ++r) h[r] = (_Float16)acc[c][jt][r];
            *(f16x4*)(outh + ((size_t)(m0*B_) + n)*CO_ + o) = h;
        }
    }
}

// ---------------- final: identity GEMM + BN2 + add + relu (f32 vector) ----------------
__global__ __launch_bounds__(256, 2) void final_kernel(
    const _Float16* __restrict__ xT,     // [NIN][B][CI] fp16
    const _Float16* __restrict__ out2T,  // [NOUT][B][CO] fp16 (raw)
    const int*   __restrict__ pool_idx,  // [NOUT][P]
    const float* __restrict__ exp_w,     // [CO][CI]
    const float* __restrict__ exp_b,     // [CO]
    const float* __restrict__ scbi2,
    float* __restrict__ out) {           // [B][CO][NOUT]
    extern __shared__ float lds[];
    float* Es   = lds;               // [128 o][SROW] (64 i used)
    float* Pool = lds + CO_*SROW;    // [128 n][SROW]
    const int t  = threadIdx.x;
    const int m0 = blockIdx.x * 32;
    const int og = t & 15, ng = t >> 4;

    #pragma unroll
    for (int r = 0; r < 32; ++r) {   // Es[o][i] = exp_w[o][i]
        int f = r*256 + t;
        int o = f >> 6, i = f & 63;
        Es[o*SROW + i] = exp_w[f];
    }
    #pragma unroll 2
    for (int r = 0; r < 32; ++r) {   // Pool[n][i] = mean_p xT[pool_idx[m][p]][b][i]
        int f   = r*256 + t;
        int col = f >> 6, i = f & 63;
        int mi  = col >> 2, b = col & 3;
        int m   = m0 + mi;
        float s = 0.f;
        #pragma unroll
        for (int p = 0; p < PP_; ++p) {
            int pp = pool_idx[m*PP_ + p];
            s += (float)xT[((size_t)pp*B_ + b)*CI_ + i];
        }
        Pool[col*SROW + i] = s * 0.25f;
    }
    __syncthreads();
    float acc[8][8];
    #pragma unroll
    for (int c = 0; c < 8; ++c)
        #pragma unroll
        for (int j = 0; j < 8; ++j) acc[c][j] = 0.f;
    #pragma unroll 2
    for (int i4 = 0; i4 < 16; ++i4) {
        float4 wv[8], gv[8];
        #pragma unroll
        for (int c = 0; c < 8; ++c)
            wv[c] = *reinterpret_cast<const float4*>(&Es[(og + 16*c)*SROW + i4*4]);
        #pragma unroll
        for (int j = 0; j < 8; ++j)
            gv[j] = *reinterpret_cast<const float4*>(&Pool[(j*16 + ng)*SROW + i4*4]);
        #pragma unroll
        for (int c = 0; c < 8; ++c)
            #pragma unroll
            for (int j = 0; j < 8; ++j) {
                acc[c][j] += wv[c].x * gv[j].x;
                acc[c][j] += wv[c].y * gv[j].y;
                acc[c][j] += wv[c].z * gv[j].z;
                acc[c][j] += wv[c].w * gv[j].w;
            }
    }
    __syncthreads();
    float* sh = lds;  // [128 n][SHST] identity (pre exp_b)
    #pragma unroll
    for (int c = 0; c < 8; ++c)
        #pragma unroll
        for (int j = 0; j < 8; ++j)
            sh[(j*16 + ng)*SHST + og + 16*c] = acc[c][j];
    __syncthreads();
    #pragma unroll 4
    for (int r = 0; r < 64; ++r) {
        int f  = r*256 + t;              // f = b*4096 + o*32 + mi
        int b  = f >> 12;
        int o  = (f >> 5) & 127;
        int mi = f & 31;
        int n  = mi*4 + b;
        float ident = sh[n*SHST + o] + exp_b[o];
        float v2 = (float)out2T[((size_t)(m0+mi)*B_ + b)*CO_ + o];
        v2 = v2 * scbi2[o] + scbi2[128 + o];
        out[((size_t)(b*CO_ + o))*NOUT_ + m0 + mi] = fmaxf(v2 + ident, 0.f);
    }
}

// ---------------- launch ----------------
extern "C" void kernel_launch(void* const* d_in, const int* in_sizes, int n_in,
                              void* d_out, int out_size, void* d_ws, size_t ws_size,
                              hipStream_t stream) {
    const float* x        = (const float*)d_in[0];
    const float* off1     = (const float*)d_in[1];
    const float* off2     = (const float*)d_in[2];
    const int*   nbr1     = (const int*)  d_in[3];
    const int*   nbr2     = (const int*)  d_in[4];
    const int*   pool_idx = (const int*)  d_in[5];
    const float* wn_w1    = (const float*)d_in[6];
    const float* wn_b1    = (const float*)d_in[7];
    const float* wn_w2    = (const float*)d_in[8];
    const float* wn_b2    = (const float*)d_in[9];
    const float* W1       = (const float*)d_in[10];
    const float* W2       = (const float*)d_in[11];
    const float* bn1_g    = (const float*)d_in[12];
    const float* bn1_b    = (const float*)d_in[13];
    const float* bn2_g    = (const float*)d_in[14];
    const float* bn2_b    = (const float*)d_in[15];
    const float* exp_w    = (const float*)d_in[16];
    const float* exp_b    = (const float*)d_in[17];
    float* out = (float*)d_out;

    // workspace carve (~68.9 MB)
    char* ws = (char*)d_ws;
    float* a1      = (float*)ws;  ws += (size_t)NOUT_*KK_*4;
    float* a2      = (float*)ws;  ws += (size_t)NOUT_*KK_*4;
    float* scbi1   = (float*)ws;  ws += 256*4;
    float* scbi2   = (float*)ws;  ws += 256*4;
    float* pbuf    = (float*)ws;  ws += 128*256*4;
    _Float16* Wf1  = (_Float16*)ws; ws += (size_t)9*8192*2;
    _Float16* Wf2  = (_Float16*)ws; ws += (size_t)18*8192*2;
    _Float16* xh   = (_Float16*)ws; ws += (size_t)NIN_*B_*CI_*2;   // 33.5MB
    _Float16* o1h  = (_Float16*)ws; ws += (size_t)NOUT_*B_*CO_*2;  // 16.8MB
    _Float16* o2h  = (_Float16*)ws; ws += (size_t)NOUT_*B_*CO_*2;  // 16.8MB

    hipFuncSetAttribute(reinterpret_cast<const void*>(final_kernel),
                        hipFuncAttributeMaxDynamicSharedMemorySize, LDSZ);

    wnet_kernel<<<(NOUT_*KK_ + 255)/256, 256, 0, stream>>>(off1, off2, wn_w1, wn_b1, wn_w2, wn_b2, a1, a2);
    wpack_kernel<CI_><<<(9*8192 + 255)/256, 256, 0, stream>>>(W1, Wf1);
    wpack_kernel<CO_><<<(18*8192 + 255)/256, 256, 0, stream>>>(W2, Wf2);
    xtrans_kernel<<<dim3(NIN_/64, B_), 256, 0, stream>>>(x, xh);

    conv_mfma_kernel<CI_, 9><<<NOUT_/32, 256, 0, stream>>>(xh, Wf1, nbr1, a1, o1h);
    stats_kernel<<<128, 256, 0, stream>>>(o1h, pbuf);
    bnparams_kernel<<<1, 128, 0, stream>>>(pbuf, bn1_g, bn1_b, scbi1);
    bnrelu_kernel<<<4096, 256, 0, stream>>>(o1h, scbi1);

    conv_mfma_kernel<CO_, 18><<<NOUT_/32, 256, 0, stream>>>(o1h, Wf2, nbr2, a2, o2h);
    stats_kernel<<<128, 256, 0, stream>>>(o2h, pbuf);
    bnparams_kernel<<<1, 128, 0, stream>>>(pbuf, bn2_g, bn2_b, scbi2);

    final_kernel<<<NOUT_/32, 256, LDSZ, stream>>>(xh, o2h, pool_idx, exp_w, exp_b, scbi2, out);
}